// Round 7
// baseline (615.081 us; speedup 1.0000x reference)
//
#include <hip/hip_runtime.h>
#include <math.h>

#define DIM 128
#define TR 32          // nodes per fused block
#define SAF_STRIDE 132 // fp32 accum row stride (128 + 4 pad)

typedef __attribute__((ext_vector_type(8))) short bf16x8;
typedef __attribute__((ext_vector_type(4))) float f32x4;

__device__ __forceinline__ ushort f2bf(float f) {
    union { float f; unsigned u; } v; v.f = f;
    unsigned u = v.u;
    return (ushort)((u + 0x7FFFu + ((u >> 16) & 1u)) >> 16);  // RNE
}

// zero deg+cnt (2N floats) and build Wt[n][k] = bf16(W[k][n]) in one launch
__global__ void init_kernel(const float* __restrict__ W, ushort* __restrict__ Wt,
                            float* __restrict__ deg_cnt, int twoN) {
    int i = blockIdx.x * blockDim.x + threadIdx.x;
    if (i < twoN) deg_cnt[i] = 0.f;
    if (i < DIM * DIM) {
        int k = i >> 7, n = i & 127;
        Wt[n * DIM + k] = f2bf(W[k * DIM + n]);
    }
}

__global__ void fill_zero(float* p, int n) {
    int i = blockIdx.x * blockDim.x + threadIdx.x;
    if (i < n) p[i] = 0.f;
}

__global__ void fill_zero4(float4* p, int n4) {
    int i = blockIdx.x * blockDim.x + threadIdx.x;
    if (i < n4) p[i] = make_float4(0.f, 0.f, 0.f, 0.f);
}

// cnt[col]++ ; deg[col] += ew[e]
__global__ void count_deg_kernel(const int* __restrict__ ei, const float* __restrict__ ew,
                                 int* __restrict__ cnt, float* __restrict__ deg, int E) {
    int e = blockIdx.x * blockDim.x + threadIdx.x;
    if (e < E) {
        int col = ei[E + e];
        atomicAdd(&cnt[col], 1);
        atomicAdd(&deg[col], ew[e]);
    }
}

// per-block exclusive scan of cnt -> start_local, blockSums
__global__ __launch_bounds__(256) void scan1_kernel(const int* __restrict__ cnt,
                                                    int* __restrict__ start_local,
                                                    int* __restrict__ blockSums, int N) {
    __shared__ int s[256];
    int t = threadIdx.x;
    int i = blockIdx.x * 256 + t;
    int c = (i < N) ? cnt[i] : 0;
    s[t] = c;
    __syncthreads();
#pragma unroll
    for (int off = 1; off < 256; off <<= 1) {
        int v = (t >= off) ? s[t - off] : 0;
        __syncthreads();
        s[t] += v;
        __syncthreads();
    }
    if (i < N) start_local[i] = s[t] - c;
    if (t == 255) blockSums[blockIdx.x] = s[t];
}

// single-block exclusive scan of blockSums (nb <= 512)
__global__ __launch_bounds__(512) void scan2_kernel(int* __restrict__ blockSums, int nb) {
    __shared__ int s[512];
    int t = threadIdx.x;
    int c = (t < nb) ? blockSums[t] : 0;
    s[t] = c;
    __syncthreads();
#pragma unroll
    for (int off = 1; off < 512; off <<= 1) {
        int v = (t >= off) ? s[t - off] : 0;
        __syncthreads();
        s[t] += v;
        __syncthreads();
    }
    if (t < nb) blockSums[t] = s[t] - c;
}

// row_start/cursor = global prefix (row_start has N+1 entries); deg -> dinv (fused)
__global__ void scan3_kernel(const int* __restrict__ start_local, const int* __restrict__ blockSums,
                             int* __restrict__ row_start, int* __restrict__ cursor,
                             float* __restrict__ deg, int N, int E) {
    int i = blockIdx.x * blockDim.x + threadIdx.x;
    if (i < N) {
        int rs = start_local[i] + blockSums[i >> 8];
        row_start[i] = rs;
        cursor[i] = rs;
        float d = deg[i];
        deg[i] = d > 0.f ? rsqrtf(d) : 0.f;
    } else if (i == N) {
        row_start[N] = E;
    }
}

// CSR fill (packed 8B): p = cursor[col]++; csr[p] = {src | (col%32)<<20, bits(dinv[row]*ew)}
// dinv[col] is applied per-row in the fused kernel (saves a random read here).
__global__ void csr_fill_kernel(const int* __restrict__ ei, const float* __restrict__ ew,
                                const float* __restrict__ dinv, int* __restrict__ cursor,
                                int2* __restrict__ csr, int E) {
    int e = blockIdx.x * blockDim.x + threadIdx.x;
    if (e < E) {
        int row = ei[e];
        int col = ei[E + e];
        int p = atomicAdd(&cursor[col], 1);
        float w = dinv[row] * ew[e];
        csr[p] = make_int2(row | ((col & 31) << 20), __float_as_int(w));
    }
}

// Fused: edge-parallel gather -> fp32 LDS (ds_add_f32) -> scale by dinv[col], cvt bf16 ->
// MFMA 32x128 @ 128x128 -> bias + LN + GELU + residual.
// 256 threads = 8 groups of 32 lanes streaming the block's contiguous CSR range (round-robin,
// all x-row loads independent -> high MLP), then 4 waves do the MFMA GEMM as in round 6.
__global__ __launch_bounds__(256) void gather_mfma_ln_kernel(
        const int2* __restrict__ csr, const int* __restrict__ row_start,
        const float* __restrict__ dinv, const float* __restrict__ x,
        const ushort* __restrict__ Wt, const float* __restrict__ b,
        const float* __restrict__ gamma, const float* __restrict__ beta,
        float* __restrict__ out, int N) {
    __shared__ float sAf[TR][SAF_STRIDE];  // 16.9 KB fp32 accumulator tile
    __shared__ float redS[4][16];
    __shared__ float redQ[4][16];

    const int tid  = threadIdx.x;
    const int l32  = tid & 31;
    const int g32  = tid >> 5;       // gather group 0..7
    const int lane = tid & 63;
    const int w    = tid >> 6;       // wave 0..3
    const int row0 = blockIdx.x * TR;

    // zero the accumulator tile
    {
        float4* p = (float4*)&sAf[0][0];
        const int tot = TR * SAF_STRIDE / 4;  // 1056
        for (int i = tid; i < tot; i += 256) p[i] = make_float4(0.f, 0.f, 0.f, 0.f);
    }
    __syncthreads();

    // ---- Phase A: edge-parallel gather over the block's contiguous CSR range ----
    {
        int rend = row0 + TR; if (rend > N) rend = N;
        const int s0 = row_start[row0];
        const int e0 = row_start[rend];
        const float4* xv = (const float4*)x;
        for (int j = s0 + g32; j < e0; j += 8) {
            int2 pk = csr[j];                       // broadcast within group
            int src  = pk.x & 0xFFFFF;
            int loc  = ((unsigned)pk.x) >> 20;
            float wt = __int_as_float(pk.y);
            float4 v = xv[(size_t)src * 32 + l32];
            float* dst = &sAf[loc][l32 * 4];
            atomicAdd(dst + 0, v.x * wt);           // ds_add_f32
            atomicAdd(dst + 1, v.y * wt);
            atomicAdd(dst + 2, v.z * wt);
            atomicAdd(dst + 3, v.w * wt);
        }
    }
    __syncthreads();

    // ---- Phase B: MFMA GEMM (wave w -> row-tile tm=w&1, col-tiles tnb..tnb+3) ----
    const int m16  = lane & 15;
    const int quad = lane >> 4;          // 0..3
    const int tm   = w & 1;
    const int tnb  = (w >> 1) * 4;

    const int arow_idx = 16 * tm + m16;
    const int anode = row0 + arow_idx;
    const float dscale = (anode < N) ? dinv[anode] : 0.f;  // dinv[col] factor

    bf16x8 afrag[4];
    const float* arow = &sAf[arow_idx][0];
#pragma unroll
    for (int kb = 0; kb < 4; ++kb) {
        float4 f0 = *(const float4*)(arow + kb * 32 + quad * 8);
        float4 f1 = *(const float4*)(arow + kb * 32 + quad * 8 + 4);
        bf16x8 af;
        af[0] = (short)f2bf(f0.x * dscale); af[1] = (short)f2bf(f0.y * dscale);
        af[2] = (short)f2bf(f0.z * dscale); af[3] = (short)f2bf(f0.w * dscale);
        af[4] = (short)f2bf(f1.x * dscale); af[5] = (short)f2bf(f1.y * dscale);
        af[6] = (short)f2bf(f1.z * dscale); af[7] = (short)f2bf(f1.w * dscale);
        afrag[kb] = af;
    }

    f32x4 acc[4];
#pragma unroll
    for (int t = 0; t < 4; ++t) { acc[t][0] = 0.f; acc[t][1] = 0.f; acc[t][2] = 0.f; acc[t][3] = 0.f; }

#pragma unroll
    for (int kb = 0; kb < 4; ++kb) {
#pragma unroll
        for (int t = 0; t < 4; ++t) {
            const ushort* bp = Wt + (size_t)((tnb + t) * 16 + m16) * DIM + kb * 32 + quad * 8;
            bf16x8 bfrag = *(const bf16x8*)bp;      // global 16B, L1-resident
            acc[t] = __builtin_amdgcn_mfma_f32_16x16x32_bf16(afrag[kb], bfrag, acc[t], 0, 0, 0);
        }
    }

    // ---- bias (per col) before LN stats ----
    float gcol[4], becol[4];
#pragma unroll
    for (int t = 0; t < 4; ++t) {
        int col = (tnb + t) * 16 + m16;
        float bc = b[col];
        gcol[t]  = gamma[col];
        becol[t] = beta[col];
#pragma unroll
        for (int i = 0; i < 4; ++i) acc[t][i] += bc;
    }

    // ---- LN stats: rows 4*quad+i; reduce this wave's 64 cols via shuffles ----
    float s[4], sq[4];
#pragma unroll
    for (int i = 0; i < 4; ++i) {
        s[i]  = acc[0][i] + acc[1][i] + acc[2][i] + acc[3][i];
        sq[i] = acc[0][i]*acc[0][i] + acc[1][i]*acc[1][i] + acc[2][i]*acc[2][i] + acc[3][i]*acc[3][i];
    }
#pragma unroll
    for (int off = 1; off <= 8; off <<= 1) {
#pragma unroll
        for (int i = 0; i < 4; ++i) {
            s[i]  += __shfl_xor(s[i], off);
            sq[i] += __shfl_xor(sq[i], off);
        }
    }
    if (m16 == 0) {
#pragma unroll
        for (int i = 0; i < 4; ++i) {
            redS[w][quad * 4 + i] = s[i];
            redQ[w][quad * 4 + i] = sq[i];
        }
    }
    __syncthreads();

    // ---- finish LN + GELU + residual, store ----
#pragma unroll
    for (int i = 0; i < 4; ++i) {
        int rloc = quad * 4 + i;
        float tot  = redS[w][rloc] + redS[w ^ 2][rloc];   // partner wave shares tm
        float totq = redQ[w][rloc] + redQ[w ^ 2][rloc];
        float mu   = tot * (1.0f / DIM);
        float var  = totq * (1.0f / DIM) - mu * mu;
        float rstd = rsqrtf(var + 1e-5f);
        int r = row0 + 16 * tm + rloc;
        if (r < N) {
#pragma unroll
            for (int t = 0; t < 4; ++t) {
                int col = (tnb + t) * 16 + m16;
                float l = (acc[t][i] - mu) * rstd * gcol[t] + becol[t];
                float g = 0.5f * l * (1.0f + erff(l * 0.70710678118654752f));
                out[(size_t)r * DIM + col] = x[(size_t)r * DIM + col] + g;
            }
        }
    }
}

// ---------------- fallback path (small workspace): atomic scatter + fp32 gemm_ln ----------------
__global__ void deg_kernel(const int* __restrict__ ei, const float* __restrict__ ew,
                           float* __restrict__ deg, int E) {
    int e = blockIdx.x * blockDim.x + threadIdx.x;
    if (e < E) atomicAdd(&deg[ei[E + e]], ew[e]);
}

__global__ void dinv_kernel(float* deg, int N) {
    int i = blockIdx.x * blockDim.x + threadIdx.x;
    if (i < N) {
        float d = deg[i];
        deg[i] = d > 0.f ? rsqrtf(d) : 0.f;
    }
}

__global__ void scatter_kernel(const int* __restrict__ ei, const float* __restrict__ ew,
                               const float* __restrict__ dinv, const float* __restrict__ x,
                               float* __restrict__ out, int E) {
    int t = blockIdx.x * blockDim.x + threadIdx.x;
    int e = t >> 5;
    if (e >= E) return;
    int lane = t & 31;
    int row = ei[e];
    int col = ei[E + e];
    float w = dinv[row] * ew[e] * dinv[col];
    float4 v = *(const float4*)(x + (size_t)row * DIM + (lane << 2));
    float* dst = out + (size_t)col * DIM + (lane << 2);
    atomicAdd(dst + 0, v.x * w);
    atomicAdd(dst + 1, v.y * w);
    atomicAdd(dst + 2, v.z * w);
    atomicAdd(dst + 3, v.w * w);
}

__global__ __launch_bounds__(256) void gemm_ln_kernel(const float* __restrict__ x,
                                                      const float* __restrict__ W,
                                                      const float* __restrict__ b,
                                                      const float* __restrict__ gamma,
                                                      const float* __restrict__ beta,
                                                      float* __restrict__ out, int N) {
    __shared__ float sT[DIM][TR + 4];
    const int tid = threadIdx.x;
    const int row0 = blockIdx.x * TR;
    {
        int r = tid >> 3;
        int c0 = (tid & 7) << 4;
        int rr = row0 + r; if (rr > N - 1) rr = N - 1;
        const float4* src = (const float4*)(out + (size_t)rr * DIM + c0);
#pragma unroll
        for (int i = 0; i < 4; ++i) {
            float4 v = src[i];
            int c = c0 + i * 4;
            sT[c + 0][r] = v.x; sT[c + 1][r] = v.y; sT[c + 2][r] = v.z; sT[c + 3][r] = v.w;
        }
    }
    __syncthreads();
    const int tx = tid & 31;
    const int ty = tid >> 5;
    float acc[4][4] = {};
    const float4* Wv = (const float4*)W;
#pragma unroll 4
    for (int k = 0; k < DIM; ++k) {
        float4 wv = Wv[k * 32 + tx];
        float4 a  = *(const float4*)(&sT[k][ty * 4]);
        acc[0][0] += a.x * wv.x; acc[0][1] += a.x * wv.y; acc[0][2] += a.x * wv.z; acc[0][3] += a.x * wv.w;
        acc[1][0] += a.y * wv.x; acc[1][1] += a.y * wv.y; acc[1][2] += a.y * wv.z; acc[1][3] += a.y * wv.w;
        acc[2][0] += a.z * wv.x; acc[2][1] += a.z * wv.y; acc[2][2] += a.z * wv.z; acc[2][3] += a.z * wv.w;
        acc[3][0] += a.w * wv.x; acc[3][1] += a.w * wv.y; acc[3][2] += a.w * wv.z; acc[3][3] += a.w * wv.w;
    }
    float4 b4 = ((const float4*)b)[tx];
#pragma unroll
    for (int i = 0; i < 4; ++i) {
        acc[i][0] += b4.x; acc[i][1] += b4.y; acc[i][2] += b4.z; acc[i][3] += b4.w;
    }
    float4 g4  = ((const float4*)gamma)[tx];
    float4 be4 = ((const float4*)beta)[tx];
#pragma unroll
    for (int i = 0; i < 4; ++i) {
        float s  = acc[i][0] + acc[i][1] + acc[i][2] + acc[i][3];
        float sq = acc[i][0]*acc[i][0] + acc[i][1]*acc[i][1] + acc[i][2]*acc[i][2] + acc[i][3]*acc[i][3];
#pragma unroll
        for (int off = 16; off > 0; off >>= 1) {
            s  += __shfl_xor(s, off);
            sq += __shfl_xor(sq, off);
        }
        float mu   = s * (1.0f / DIM);
        float var  = sq * (1.0f / DIM) - mu * mu;
        float rstd = rsqrtf(var + 1e-5f);
        int r = row0 + ty * 4 + i;
        if (r < N) {
            float4 xr = *(const float4*)(x + (size_t)r * DIM + tx * 4);
            float lg[4] = {g4.x, g4.y, g4.z, g4.w};
            float lb[4] = {be4.x, be4.y, be4.z, be4.w};
            float lx[4] = {xr.x, xr.y, xr.z, xr.w};
            float o[4];
#pragma unroll
            for (int c = 0; c < 4; ++c) {
                float l = (acc[i][c] - mu) * rstd * lg[c] + lb[c];
                float g = 0.5f * l * (1.0f + erff(l * 0.70710678118654752f));
                o[c] = lx[c] + g;
            }
            *(float4*)(out + (size_t)r * DIM + tx * 4) = make_float4(o[0], o[1], o[2], o[3]);
        }
    }
}

extern "C" void kernel_launch(void* const* d_in, const int* in_sizes, int n_in,
                              void* d_out, int out_size, void* d_ws, size_t ws_size,
                              hipStream_t stream) {
    const float* x     = (const float*)d_in[0];
    const int*   ei    = (const int*)d_in[1];    // [2, E] int32
    const float* ew    = (const float*)d_in[2];
    const float* W     = (const float*)d_in[3];
    const float* b     = (const float*)d_in[4];
    const float* gamma = (const float*)d_in[5];
    const float* beta  = (const float*)d_in[6];
    const int N = in_sizes[0] / DIM;
    const int E = in_sizes[2];
    float* out = (float*)d_out;

    const int nb = (N + 255) / 256;

    // ws words: Wt bf16[128*128] (8192 words) | deg[N] | cnt[N] | start_local[N] |
    //           blockSums[512] | row_start[N+1] | cursor[N] | pad | csr int2[E]
    size_t hdr_words = 8192 + (size_t)5 * N + 1 + 512;
    hdr_words = (hdr_words + 1) & ~(size_t)1;
    size_t ws_need = (hdr_words + (size_t)2 * E) * sizeof(float);

    if (ws_size >= ws_need && nb <= 512 && N < (1 << 20)) {
        ushort* Wt         = (ushort*)d_ws;
        float*  deg        = (float*)d_ws + 8192;
        int*    cnt        = (int*)(deg + N);
        int*    start_local= cnt + N;
        int*    blockSums  = start_local + N;
        int*    row_start  = blockSums + 512;        // N+1 entries
        int*    cursor     = row_start + N + 1;
        int2*   csr        = (int2*)((float*)d_ws + hdr_words);

        int initn = 2 * N > DIM * DIM ? 2 * N : DIM * DIM;
        init_kernel<<<(initn + 255) / 256, 256, 0, stream>>>(W, Wt, deg, 2 * N);
        count_deg_kernel<<<(E + 255) / 256, 256, 0, stream>>>(ei, ew, cnt, deg, E);
        scan1_kernel<<<nb, 256, 0, stream>>>(cnt, start_local, blockSums, N);
        scan2_kernel<<<1, 512, 0, stream>>>(blockSums, nb);
        scan3_kernel<<<(N + 256) / 256, 256, 0, stream>>>(start_local, blockSums, row_start, cursor, deg, N, E);
        csr_fill_kernel<<<(E + 255) / 256, 256, 0, stream>>>(ei, ew, deg, cursor, csr, E);

        gather_mfma_ln_kernel<<<(N + TR - 1) / TR, 256, 0, stream>>>(
            csr, row_start, deg, x, Wt, b, gamma, beta, out, N);
    } else {
        float* deg = (float*)d_ws;
        int n4 = N * DIM / 4;
        fill_zero4<<<(n4 + 255) / 256, 256, 0, stream>>>((float4*)out, n4);
        fill_zero<<<nb, 256, 0, stream>>>(deg, N);
        deg_kernel<<<(E + 255) / 256, 256, 0, stream>>>(ei, ew, deg, E);
        dinv_kernel<<<nb, 256, 0, stream>>>(deg, N);
        long long sthreads = (long long)E * 32;
        scatter_kernel<<<(int)((sthreads + 255) / 256), 256, 0, stream>>>(ei, ew, deg, x, out, E);
        gemm_ln_kernel<<<(N + TR - 1) / TR, 256, 0, stream>>>(x, W, b, gamma, beta, out, N);
    }
}